// Round 1
// baseline (122.979 us; speedup 1.0000x reference)
//
#include <hip/hip_runtime.h>
#include <stdint.h>

typedef unsigned long long u64;
typedef unsigned int u32;

#define VOX     32768      // 32*32*32
#define KCAP    512        // candidate cap (matches reference K; npos <= NPTS=400)
#define MAXEV   100        // max_events
#define NBRCAP  26         // geometric max conflicts per point (26-neighborhood)
#define NTHREADS 512
#define F4_PT      (VOX / 4 / NTHREADS)        // 16 energy float4 per thread
#define OUT_F4_PT  (2 * VOX / 4 / NTHREADS)    // 32 output float4 per thread

// dist < 2.0 on integer coords  <=>  Chebyshev distance <= 1 (3x3x3 cube)
// Priority key: (float_bits(val) << 32) | ~vox  — vals > 0 so float bits are
// monotone; higher val => bigger key; tie => lower vox => bigger key. Keys
// unique (voxels unique). srank = rank among ALL candidates (reference
// truncation is on top_k position, not kept-rank).
//
// Session pricing of alternatives (do not retry):
//  - R8: nontemporal ld/st => +9 us (input is L2/L3-hot from harness restore).
//  - R10: single-kernel fusion w/ done[f] counter + __threadfence() => 6x
//    regression (per-block device fence = L2 writeback/invalidate).
//  - R5: per-wave global atomics on packed counters => 6x regression
//    (cacheline ping-pong across XCDs).
//  - THIS ROUND: true fusion with ZERO inter-block communication — one block
//    per frame does read+collect+zerofill+NMS+scatter entirely in LDS.
//    Removes: 1 launch, inter-kernel gap, grec/gcnt/gnz global round-trip,
//    kernel-2 gather phase. Workspace now unused.

__global__ __launch_bounds__(NTHREADS) void fused_kernel(
    const float* __restrict__ x, float* __restrict__ out)
{
    const int f   = blockIdx.x;
    const int tid = threadIdx.x;

    __shared__ unsigned short smap[VOX];            // voxel -> slot (0xFFFF none), 64 KB
    __shared__ u64   skey[KCAP];                    // candidate keys, 4 KB
    __shared__ short srank[KCAP];
    __shared__ unsigned char status[KCAP];          // 0 undecided, 1 kept, 2 suppressed
    __shared__ unsigned short pnbr[KCAP * NBRCAP];  // higher-priority conflicts, 26 KB
    __shared__ int s_cnt, s_nz, s_nkept, s_undec;

    // ---- 1. issue ALL energy loads first (16 float4 / thread, coalesced) ----
    const float4* e4 = (const float4*)(x + (size_t)f * 2 * VOX);
    float4 v[F4_PT];
    #pragma unroll
    for (int h = 0; h < F4_PT; ++h)
        v[h] = e4[tid + h * NTHREADS];

    // ---- 2. init LDS map + counters while loads are in flight ----
    if (tid == 0) { s_cnt = 0; s_nz = 0; s_nkept = 0; }
    {
        u32* m32 = (u32*)smap;
        #pragma unroll
        for (int h = 0; h < VOX / 2 / NTHREADS; ++h)
            m32[tid + h * NTHREADS] = 0xFFFFFFFFu;
    }

    // ---- 3. zero-fill this frame's output slice while loads are in flight ----
    float4* o4 = (float4*)(out + (size_t)f * 2 * VOX);
    {
        const float4 z = make_float4(0.f, 0.f, 0.f, 0.f);
        #pragma unroll
        for (int h = 0; h < OUT_F4_PT; ++h)
            o4[tid + h * NTHREADS] = z;
    }
    __syncthreads();   // smap init complete before collection writes

    // ---- 4. scan loaded values, collect positives straight into skey/smap ----
    bool anynz = false;
    #pragma unroll
    for (int h = 0; h < F4_PT; ++h) {
        int vbase = (tid + h * NTHREADS) * 4;            // voxel of component 0
        float vv[4] = {v[h].x, v[h].y, v[h].z, v[h].w};
        #pragma unroll
        for (int cc = 0; cc < 4; ++cc) {
            float val = vv[cc];
            anynz |= (val != 0.f);
            if (val > 0.f) {                             // rare (~0.8/thread)
                int slot = atomicAdd(&s_cnt, 1);         // LDS atomic: cheap
                if (slot < KCAP) {
                    int vox = vbase + cc;
                    skey[slot] = ((u64)__float_as_uint(val) << 32) | (u64)(~(u32)vox);
                    smap[vox]  = (unsigned short)slot;
                }
            }
        }
    }
    if (anynz) s_nz = 1;                                 // benign race
    __syncthreads();

    const int n = min(s_cnt, KCAP);

    if (s_nz == 0) {
        // empty frame: pass input through. Same per-thread index mapping as
        // the zero-fill above => same thread rewrites same addresses =>
        // program-order guarantees the copy wins. (Rare path.)
        const float4* x4 = (const float4*)(x + (size_t)f * 2 * VOX);
        #pragma unroll
        for (int h = 0; h < OUT_F4_PT; ++h)
            o4[tid + h * NTHREADS] = x4[tid + h * NTHREADS];
        return;
    }

    // ---- 5. rank (broadcast loop) + conflict lists via 26 smap probes ----
    int pcnt = 0;
    float mag = 0.f;
    if (tid < n) {
        const u64 kt = skey[tid];
        int rank = 0;
        #pragma unroll 8
        for (int i = 0; i < n; ++i)
            rank += (skey[i] > kt);
        srank[tid] = (short)rank;

        const int vox = (int)(~(u32)kt) & (VOX - 1);
        // prefetch magnitude for ALL candidates now; latency hides under the
        // propagation rounds, scatter at the end consumes it from a register.
        mag = x[(size_t)f * 2 * VOX + VOX + vox];

        const int zt = vox >> 10, yt = (vox >> 5) & 31, xt = vox & 31;
        #pragma unroll
        for (int dz = -1; dz <= 1; ++dz) {
            int z = zt + dz; if ((unsigned)z >= 32) continue;
            #pragma unroll
            for (int dy = -1; dy <= 1; ++dy) {
                int yy = yt + dy; if ((unsigned)yy >= 32) continue;
                #pragma unroll
                for (int dx = -1; dx <= 1; ++dx) {
                    int xx = xt + dx; if ((unsigned)xx >= 32) continue;
                    int nv = (z << 10) | (yy << 5) | xx;
                    if (nv == vox) continue;
                    unsigned short m = smap[nv];
                    if (m != 0xFFFFu && skey[m] > kt)
                        pnbr[tid * NBRCAP + pcnt++] = m;
                }
            }
        }
        status[tid] = (pcnt == 0) ? (unsigned char)1 : (unsigned char)0;
    }
    __syncthreads();

    // ---- 6. parallel greedy resolution (monotone label propagation) ----
    for (int round = 0; round < KCAP; ++round) {
        if (tid == 0) s_undec = 0;
        __syncthreads();
        if (tid < n && status[tid] == 0) {
            bool anyKept = false, anyUndec = false;
            for (int p = 0; p < pcnt; ++p) {
                unsigned char s = status[pnbr[tid * NBRCAP + p]];
                anyKept  |= (s == 1);
                anyUndec |= (s == 0);
            }
            if (anyKept)        status[tid] = 2;
            else if (!anyUndec) status[tid] = 1;
            else                s_undec = 1;        // benign race: all write 1
        }
        __syncthreads();
        if (s_undec == 0) break;
    }

    // ---- 7. count kept, rank truncation, scatter survivors ----
    if (tid < n && status[tid] == 1) atomicAdd(&s_nkept, 1);
    __syncthreads();
    const int nkept = s_nkept;
    if (tid < n && status[tid] == 1 &&
        !(nkept > MAXEV && srank[tid] >= MAXEV)) {
        u64 k = skey[tid];
        int   vox = (int)(~(u32)k) & (VOX - 1);
        float val = __uint_as_float((u32)(k >> 32));
        float* of = out + (size_t)f * 2 * VOX;
        // zero-fill stores were drained at the intervening __syncthreads
        // (compiler emits s_waitcnt vmcnt(0) before s_barrier), so these
        // scatter stores safely overwrite the zeros.
        of[vox]       = val;   // exact energy copy
        of[VOX + vox] = mag;   // exact magnitude copy (prefetched in step 5)
    }
}

extern "C" void kernel_launch(void* const* d_in, const int* in_sizes, int n_in,
                              void* d_out, int out_size, void* d_ws, size_t ws_size,
                              hipStream_t stream) {
    const float* x = (const float*)d_in[0];
    float* out = (float*)d_out;
    int frames = in_sizes[0] / (2 * VOX);   // B*T = 256
    (void)d_ws; (void)ws_size;              // workspace no longer used

    fused_kernel<<<frames, NTHREADS, 0, stream>>>(x, out);
}